// Round 13
// baseline (294.603 us; speedup 1.0000x reference)
//
#include <hip/hip_runtime.h>
#include <math.h>

#define NN 16384
#define EE 65536
#define BB 512
#define VV 32000

typedef unsigned short us_t;
typedef unsigned int u32_t;
typedef __attribute__((ext_vector_type(4))) float f32x4;
typedef __attribute__((ext_vector_type(8))) short bf16x8;
typedef __attribute__((ext_vector_type(4))) unsigned int u32x4;

__device__ __forceinline__ float bf2f(unsigned int u) {
  return __uint_as_float((u & 0xffffu) << 16);
}
__device__ __forceinline__ unsigned short f2bf(float f) {
  unsigned int x = __float_as_uint(f);
  unsigned int r = (x + 0x7fffu + ((x >> 16) & 1u)) >> 16;
  return (unsigned short)r;
}
__device__ __forceinline__ bf16x8 ntld(const us_t* p) {
  return __builtin_nontemporal_load((const bf16x8*)p);
}
__device__ __forceinline__ void ntst(us_t* p, u32_t a, u32_t b, u32_t c, u32_t d) {
  u32x4 v = {a, b, c, d};
  __builtin_nontemporal_store(v, (u32x4*)p);
}
__device__ __forceinline__ float wsum(float v) {
#pragma unroll
  for (int o = 32; o; o >>= 1) v += __shfl_xor(v, o, 64);
  return v;
}
__device__ __forceinline__ float redu16(float v) {
  v += __shfl_xor(v, 1, 64);
  v += __shfl_xor(v, 2, 64);
  v += __shfl_xor(v, 4, 64);
  v += __shfl_xor(v, 8, 64);
  return v;
}
__device__ __forceinline__ float lrelu(float x) { return x > 0.f ? x : 0.2f * x; }

// ---------------- dtype probe ----------------
__global__ void k_detect(const void* emb, int* flag) {
  if (threadIdx.x == 0 && blockIdx.x == 0) {
    const us_t* u = (const us_t*)emb;
    int ok = 1;
    for (int i = 0; i < 128; i++) {
      float v = bf2f((unsigned int)u[i]);
      if (!(fabsf(v) <= 0.13f)) { ok = 0; break; }
    }
    *flag = ok;  // 1 => inputs bf16, 0 => f32
  }
}

// ---------------- fused prep: convert + transpose weights ----------------
struct PrepArgs {
  const void* src[17];
  void* dst[17];
  int n[17];
  int kind[17];   // 0 cvt f32, 1 cvt bf16, 2 g1W T, 3 g2W T, 4 W2 T (192x192)
  int start[18];
};

__global__ void k_prep(PrepArgs pa, const int* __restrict__ flag) {
  int blk = blockIdx.x;
  int s = 0;
  while (s < 16 && blk >= pa.start[s + 1]) s++;
  int i = (blk - pa.start[s]) * 256 + threadIdx.x;
  if (i >= pa.n[s]) return;
  float v = (*flag) ? bf2f((unsigned int)((const us_t*)pa.src[s])[i])
                    : ((const float*)pa.src[s])[i];
  int kind = pa.kind[s];
  if (kind == 0) {
    ((float*)pa.dst[s])[i] = v;
  } else if (kind == 1) {
    ((us_t*)pa.dst[s])[i] = f2bf(v);
  } else if (kind == 2) {  // [3][64][1024] -> [3][1024][64]
    int ii = i >> 16, r = i & 65535, k = r >> 10, col = r & 1023;
    ((us_t*)pa.dst[s])[(ii << 16) + col * 64 + k] = f2bf(v);
  } else if (kind == 3) {  // [3][1024][64] -> [3][64][1024]
    int ii = i >> 16, r = i & 65535, k = r >> 6, col = r & 63;
    ((us_t*)pa.dst[s])[(ii << 16) + col * 1024 + k] = f2bf(v);
  } else {  // [192][192] -> [192][192]^T
    int k = i / 192, col = i % 192;
    ((us_t*)pa.dst[s])[col * 192 + k] = f2bf(v);
  }
}

// ---------------- Waspack: [96 cols][64 k] bf16; col = i*32 + sd*16 + h ----------------
__global__ void k_prepWa(const void* __restrict__ g1Wraw,
                         const float* __restrict__ g1as, const float* __restrict__ g1ad,
                         const int* __restrict__ flag, us_t* __restrict__ Waspack) {
  int gid = blockIdx.x * 256 + threadIdx.x;
  if (gid >= 96 * 64) return;
  int c = gid >> 6, k = gid & 63;
  int i = c >> 5, sd = (c >> 4) & 1, h = c & 15;
  const float* av = (sd ? g1ad : g1as) + i * 1024 + h * 64;
  size_t base = (size_t)i * 65536 + (size_t)k * 1024 + h * 64;
  int isbf = *flag;
  float s = 0.f;
  for (int d = 0; d < 64; d++) {
    float wv = isbf ? bf2f((unsigned int)((const us_t*)g1Wraw)[base + d])
                    : ((const float*)g1Wraw)[base + d];
    s += wv * av[d];
  }
  Waspack[c * 64 + k] = f2bf(s);
}

// ---------------- embedding gather + interest softmax ----------------
__global__ void k_embed(const int* __restrict__ x, const void* __restrict__ embr,
                        const void* __restrict__ wintr, const int* __restrict__ flag,
                        us_t* __restrict__ e_bf, float* __restrict__ g) {
  int gid = blockIdx.x * blockDim.x + threadIdx.x;
  int n = gid >> 6, lane = gid & 63;
  if (n >= NN) return;
  int isbf = *flag;
  size_t ei = (size_t)x[n] * 64 + lane;
  float v = isbf ? bf2f((unsigned int)((const us_t*)embr)[ei]) : ((const float*)embr)[ei];
  e_bf[(size_t)n * 64 + lane] = f2bf(v);
  float w0, w1, w2;
  if (isbf) {
    const us_t* w = (const us_t*)wintr;
    w0 = bf2f(w[lane * 3 + 0]); w1 = bf2f(w[lane * 3 + 1]); w2 = bf2f(w[lane * 3 + 2]);
  } else {
    const float* w = (const float*)wintr;
    w0 = w[lane * 3 + 0]; w1 = w[lane * 3 + 1]; w2 = w[lane * 3 + 2];
  }
  float t0 = wsum(v * w0), t1 = wsum(v * w1), t2 = wsum(v * w2);
  if (lane == 0) {
    float l0 = t0 / 0.1f, l1 = t1 / 0.1f, l2 = t2 / 0.1f;
    float m = fmaxf(l0, fmaxf(l1, l2));
    float p0 = __expf(l0 - m), p1 = __expf(l1 - m), p2 = __expf(l2 - m);
    float inv = 1.0f / (p0 + p1 + p2);
    g[n * 4 + 0] = p0 * inv; g[n * 4 + 1] = p1 * inv;
    g[n * 4 + 2] = p2 * inv; g[n * 4 + 3] = 0.f;
  }
}

// ---------------- compact per-interest CSR build (valid edges only) ----------------
__global__ void k_countv(const int* __restrict__ ei, const float* __restrict__ g,
                         int* __restrict__ countsv) {
  int e = blockIdx.x * 256 + threadIdx.x;
  if (e >= EE) return;
  int s = ei[e], d = ei[EE + e];
  const float thr = 1.0f / 3.0f;
#pragma unroll
  for (int i = 0; i < 3; i++) {
    if (g[s * 4 + i] > thr && g[d * 4 + i] > thr)
      atomicAdd(&countsv[i * NN + d], 1);
  }
}

__global__ void k_scanv(const int* __restrict__ counts, int* __restrict__ offsets) {
  __shared__ int part[256];
  __shared__ int excl[257];
  int t = threadIdx.x;
  int base = t * 192;
  int s = 0;
  for (int j = 0; j < 192; j++) s += counts[base + j];
  part[t] = s;
  __syncthreads();
  if (t == 0) {
    int run = 0;
    for (int j = 0; j < 256; j++) { excl[j] = run; run += part[j]; }
    excl[256] = run;
  }
  __syncthreads();
  int run = excl[t];
  for (int j = 0; j < 192; j++) { offsets[base + j] = run; run += counts[base + j]; }
  if (t == 255) offsets[3 * NN] = excl[256];
}

__global__ void k_fillv(const int* __restrict__ ei, const float* __restrict__ g,
                        const float* __restrict__ eatt,
                        const int* __restrict__ offsetsv, int* __restrict__ fillposv,
                        int2* __restrict__ edgesC, float* __restrict__ easrcP) {
  int e = blockIdx.x * 256 + threadIdx.x;
  if (e >= EE) return;
  int s = ei[e], d = ei[EE + e];
  const float thr = 1.0f / 3.0f;
#pragma unroll
  for (int i = 0; i < 3; i++) {
    float gs = g[s * 4 + i];
    if (gs > thr && g[d * 4 + i] > thr) {
      int pos = offsetsv[i * NN + d] + atomicAdd(&fillposv[i * NN + d], 1);
      edgesC[pos] = make_int2(s, __float_as_int(gs));
      const float* er = &eatt[(size_t)s * 96 + i * 32];
      float* op = &easrcP[(size_t)pos * 16];
#pragma unroll
      for (int h = 0; h < 16; h++) op[h] = gs * er[h];
    }
  }
}

// ---------------- easrc: e[N,64] @ Waspack^T -> eatt[N][96] f32 ----------------
__global__ __launch_bounds__(256) void k_easrc(
    const us_t* __restrict__ e_bf, const us_t* __restrict__ Waspack,
    float* __restrict__ eatt) {
  __shared__ char As[8192];
  int t = threadIdx.x;
  int row0 = blockIdx.x * 64;
  for (int id = t; id < 512; id += 256) {
    int r = id >> 3, c = id & 7;
    uint4 v = *(const uint4*)&e_bf[(size_t)(row0 + r) * 64 + c * 8];
    *(uint4*)(As + r * 128 + ((c ^ (r & 7)) << 4)) = v;
  }
  __syncthreads();
  int wv = t >> 6, L = t & 63, li = L & 15, lq = L >> 4;
#pragma unroll
  for (int ct = 0; ct < 6; ct++) {
    f32x4 acc = {0.f, 0.f, 0.f, 0.f};
#pragma unroll
    for (int ks = 0; ks < 2; ks++) {
      int row = wv * 16 + li;
      bf16x8 af = *(const bf16x8*)(As + row * 128 + (((ks * 4 + lq) ^ (row & 7)) << 4));
      bf16x8 bfr = *(const bf16x8*)(Waspack + (size_t)(ct * 16 + li) * 64 + ks * 32 + lq * 8);
      acc = __builtin_amdgcn_mfma_f32_16x16x32_bf16(af, bfr, acc, 0, 0, 0);
    }
#pragma unroll
    for (int r = 0; r < 4; r++) {
      int row = row0 + wv * 16 + lq * 4 + r;
      eatt[(size_t)row * 96 + ct * 16 + li] = acc[r];
    }
  }
}

// ---------------- Phase A: x-space aggregation -> xagg[3][16][N][64] bf16 head-major ----
__global__ __launch_bounds__(256) void k_phaseA(
    const us_t* __restrict__ e_bf, const float* __restrict__ g,
    const float* __restrict__ eatt,
    const int* __restrict__ offsetsv, const int2* __restrict__ edgesC,
    const float* __restrict__ easrcP, us_t* __restrict__ xagg) {
  int t = threadIdx.x;
  int intr = blockIdx.y;
  int wv = t >> 6, L = t & 63;
  int n = blockIdx.x * 4 + wv;
  int h = L >> 2;
  int doff = (L & 3) * 16;
  float gn = g[n * 4 + intr];
  float ad = gn * eatt[(size_t)n * 96 + intr * 32 + 16 + h];
  float m = lrelu(gn * eatt[(size_t)n * 96 + intr * 32 + h] + ad);
  float den = 1.f;
  float acc[16];
  {
    const uint4* ep = (const uint4*)&e_bf[(size_t)n * 64 + doff];
    uint4 a = ep[0], b = ep[1];
    acc[0] = gn * bf2f(a.x);  acc[1] = gn * bf2f(a.x >> 16);
    acc[2] = gn * bf2f(a.y);  acc[3] = gn * bf2f(a.y >> 16);
    acc[4] = gn * bf2f(a.z);  acc[5] = gn * bf2f(a.z >> 16);
    acc[6] = gn * bf2f(a.w);  acc[7] = gn * bf2f(a.w >> 16);
    acc[8] = gn * bf2f(b.x);  acc[9] = gn * bf2f(b.x >> 16);
    acc[10] = gn * bf2f(b.y); acc[11] = gn * bf2f(b.y >> 16);
    acc[12] = gn * bf2f(b.z); acc[13] = gn * bf2f(b.z >> 16);
    acc[14] = gn * bf2f(b.w); acc[15] = gn * bf2f(b.w >> 16);
  }
  int beg = offsetsv[intr * NN + n], end = offsetsv[intr * NN + n + 1];
  for (int j = beg; j < end; j++) {
    int2 sg = edgesC[j];
    int s = sg.x;
    float gs = __int_as_float(sg.y);
    float l = lrelu(easrcP[(size_t)j * 16 + h] + ad);
    float p = __expf(l - m);
    den += p;
    float pg = p * gs;
    const uint4* ep = (const uint4*)&e_bf[(size_t)s * 64 + doff];
    uint4 a = ep[0], b = ep[1];
    acc[0] += pg * bf2f(a.x);  acc[1] += pg * bf2f(a.x >> 16);
    acc[2] += pg * bf2f(a.y);  acc[3] += pg * bf2f(a.y >> 16);
    acc[4] += pg * bf2f(a.z);  acc[5] += pg * bf2f(a.z >> 16);
    acc[6] += pg * bf2f(a.w);  acc[7] += pg * bf2f(a.w >> 16);
    acc[8] += pg * bf2f(b.x);  acc[9] += pg * bf2f(b.x >> 16);
    acc[10] += pg * bf2f(b.y); acc[11] += pg * bf2f(b.y >> 16);
    acc[12] += pg * bf2f(b.z); acc[13] += pg * bf2f(b.z >> 16);
    acc[14] += pg * bf2f(b.w); acc[15] += pg * bf2f(b.w >> 16);
  }
  float inv = 1.f / den;
  u32_t w[8];
#pragma unroll
  for (int kk = 0; kk < 8; kk++) {
    w[kk] = (u32_t)f2bf(acc[2 * kk] * inv) | ((u32_t)f2bf(acc[2 * kk + 1] * inv) << 16);
  }
  us_t* op = &xagg[(((size_t)intr * 16 + h) * NN + n) * 64 + doff];
  ntst(op, w[0], w[1], w[2], w[3]);
  ntst(op + 8, w[4], w[5], w[6], w[7]);
}

// ---------------- T GEMM: T = relu(xagg_h @ W1_h + b1) — contiguous 8KB tiles ----------
__global__ __launch_bounds__(256) void k_tgemm(
    const us_t* __restrict__ xagg, const us_t* __restrict__ g1Wt,
    const float* __restrict__ b1all, us_t* __restrict__ Tbuf) {
  __shared__ char As[8192];
  __shared__ char Cs[8192];
  int t = threadIdx.x;
  int n0 = blockIdx.x * 64;
  int h = blockIdx.y;
  int intr = blockIdx.z;
  const us_t* xa = xagg + (((size_t)intr * 16 + h) * NN + n0) * 64;
  const us_t* W = g1Wt + (size_t)intr * 65536 + (size_t)(h * 64) * 64;
  const float* b1 = b1all + intr * 1024 + h * 64;
  for (int id = t; id < 512; id += 256) {
    int r = id >> 3, c = id & 7;
    bf16x8 v = ntld(&xa[(size_t)r * 64 + c * 8]);
    *(bf16x8*)(As + r * 128 + ((c ^ (r & 7)) << 4)) = v;
  }
  __syncthreads();
  int wv = t >> 6, L = t & 63, li = L & 15, lq = L >> 4;
  f32x4 acc[4];
#pragma unroll
  for (int ct = 0; ct < 4; ct++) acc[ct] = {0.f, 0.f, 0.f, 0.f};
#pragma unroll
  for (int ks = 0; ks < 2; ks++) {
    int row = wv * 16 + li;
    bf16x8 af = *(const bf16x8*)(As + row * 128 + (((ks * 4 + lq) ^ (row & 7)) << 4));
#pragma unroll
    for (int ct = 0; ct < 4; ct++) {
      bf16x8 bfr = *(const bf16x8*)&W[(size_t)(ct * 16 + li) * 64 + ks * 32 + lq * 8];
      acc[ct] = __builtin_amdgcn_mfma_f32_16x16x32_bf16(af, bfr, acc[ct], 0, 0, 0);
    }
  }
#pragma unroll
  for (int ct = 0; ct < 4; ct++) {
    float bv = b1[ct * 16 + li];
#pragma unroll
    for (int r = 0; r < 4; r++) {
      int row = wv * 16 + lq * 4 + r;
      int byte = (ct * 16 + li) * 2;
      float tv = fmaxf(acc[ct][r] + bv, 0.f);
      *(us_t*)(Cs + row * 128 + (((byte >> 4) ^ (row & 7)) << 4) + (byte & 15)) = f2bf(tv);
    }
  }
  __syncthreads();
  us_t* tb = Tbuf + (((size_t)intr * 16 + h) * NN + n0) * 64;
  for (int id = t; id < 512; id += 256) {
    int r = id >> 3, c = id & 7;
    bf16x8 v = *(const bf16x8*)(Cs + r * 128 + ((c ^ (r & 7)) << 4));
    __builtin_nontemporal_store(v, (bf16x8*)&tb[(size_t)r * 64 + c * 8]);
  }
}

// ---------------- h2 GEMM: h2pre = T @ W2 + a2 dots (head-major T) ----------------
__global__ __launch_bounds__(256) void k_h2gemm(
    const us_t* __restrict__ Tbuf, const us_t* __restrict__ g2Wt,
    const float* __restrict__ g2as, const float* __restrict__ g2ad,
    float* __restrict__ h2pre_a, float* __restrict__ a2s, float* __restrict__ a2d) {
  __shared__ uint4 AsU[1024];
  __shared__ uint4 BsU[1024];
  char* As = (char*)AsU;
  char* Bs = (char*)BsU;
  int t = threadIdx.x;
  int intr = blockIdx.y;
  int row0 = blockIdx.x * 64;
  const us_t* Wt = g2Wt + (size_t)intr * 65536;
  const float* a_s = g2as + intr * 64;
  const float* a_d = g2ad + intr * 64;
  float* h2pre = h2pre_a + (size_t)intr * NN * 64;
  int wv = t >> 6, lane = t & 63, li = lane & 15, lq = lane >> 4;
  f32x4 acc[4];
#pragma unroll
  for (int sub = 0; sub < 4; sub++) acc[sub] = {0.f, 0.f, 0.f, 0.f};
  for (int kb = 0; kb < 8; kb++) {
    __syncthreads();
    for (int id = t; id < 1024; id += 256) {
      int r = id >> 4, c = id & 15;
      int k = kb * 128 + c * 8;
      int h = k >> 6, d = k & 63;
      bf16x8 v = ntld(&Tbuf[(((size_t)intr * 16 + h) * NN + row0 + r) * 64 + d]);
      *(bf16x8*)(As + r * 256 + ((c ^ (r & 15)) << 4)) = v;
      uint4 w = *(const uint4*)&Wt[(size_t)r * 1024 + kb * 128 + c * 8];
      *(uint4*)(Bs + r * 256 + ((c ^ (r & 15)) << 4)) = w;
    }
    __syncthreads();
#pragma unroll
    for (int ks = 0; ks < 4; ks++) {
      int r = wv * 16 + li;
      bf16x8 af = *(const bf16x8*)(As + r * 256 + ((((ks << 2) | lq) ^ (r & 15)) << 4));
#pragma unroll
      for (int sub = 0; sub < 4; sub++) {
        int vr = sub * 16 + li;
        bf16x8 bf_ = *(const bf16x8*)(Bs + vr * 256 + ((((ks << 2) | lq) ^ (vr & 15)) << 4));
        acc[sub] = __builtin_amdgcn_mfma_f32_16x16x32_bf16(af, bf_, acc[sub], 0, 0, 0);
      }
    }
  }
  float asv[4], adv[4];
#pragma unroll
  for (int sub = 0; sub < 4; sub++) {
    asv[sub] = a_s[sub * 16 + li];
    adv[sub] = a_d[sub * 16 + li];
  }
#pragma unroll
  for (int rr = 0; rr < 4; rr++) {
    int n = row0 + wv * 16 + lq * 4 + rr;
    float s = 0.f, d = 0.f;
#pragma unroll
    for (int sub = 0; sub < 4; sub++) {
      float hv = acc[sub][rr];
      h2pre[(size_t)n * 64 + sub * 16 + li] = hv;
      s += hv * asv[sub];
      d += hv * adv[sub];
    }
    s = redu16(s); d = redu16(d);
    if (li == 0) {
      a2s[(size_t)intr * NN + n] = s;
      a2d[(size_t)intr * NN + n] = d;
    }
  }
}

// ---------------- GAT2 aggregation (compact CSR, self-anchored) -> sess ----------------
__global__ void k_gat2_agg(const float* __restrict__ h2pre_a,
                           const float* __restrict__ a2s_a, const float* __restrict__ a2d_a,
                           const float* __restrict__ b2all,
                           const int* __restrict__ offsetsv,
                           const int2* __restrict__ edgesC, float* __restrict__ sess) {
  int intr = blockIdx.y;
  int gid = blockIdx.x * blockDim.x + threadIdx.x;
  int n = gid >> 6, lane = gid & 63;
  if (n >= NN) return;
  const float* h2pre = h2pre_a + (size_t)intr * NN * 64;
  const float* a2s = a2s_a + (size_t)intr * NN;
  const float* a2d = a2d_a + (size_t)intr * NN;
  const float* b2 = b2all + intr * 64;
  float ad = a2d[n];
  float m = lrelu(a2s[n] + ad);  // self anchor; softmax shift-invariant
  float den = 1.f;
  float acc = h2pre[(size_t)n * 64 + lane];
  int beg = offsetsv[intr * NN + n], end = offsetsv[intr * NN + n + 1];
  for (int j = beg; j < end; j++) {
    int s = edgesC[j].x;
    float l = lrelu(a2s[s] + ad);
    float p = __expf(l - m);
    den += p;
    acc += p * h2pre[(size_t)s * 64 + lane];
  }
  sess[(size_t)n * 192 + intr * 64 + lane] = acc / den + b2[lane];
}

// ---------------- scoring ----------------
__global__ __launch_bounds__(192) void k_vq1(
    const float* __restrict__ sess,
    const float* __restrict__ W1w, const float* __restrict__ W1b,
    float* __restrict__ vn, float* __restrict__ vq1) {
  __shared__ float row[192];
  int b = blockIdx.x, j = threadIdx.x;
  int li = b * 32 + 31;  // batch = repeat(arange(B),32)
  float v = sess[(size_t)li * 192 + j];
  row[j] = v;
  vn[b * 192 + j] = v;
  __syncthreads();
  float acc = W1b[j];
  for (int k = 0; k < 192; k++) acc += row[k] * W1w[k * 192 + j];
  vq1[b * 192 + j] = acc;
}

__global__ __launch_bounds__(256) void k_alpha_sg_mfma(
    const float* __restrict__ sess, const float* __restrict__ vq1,
    const us_t* __restrict__ W2T, const float* __restrict__ W2b,
    const float* __restrict__ qw, const float* __restrict__ qb,
    float* __restrict__ sg) {
  __shared__ char As[64 * 512];
  __shared__ float vq_l[2 * 192];
  __shared__ float w2b_l[192], qw_l[192];
  __shared__ float sg_l[2 * 192];
  int t = threadIdx.x;
  int n0 = blockIdx.x * 64;
  if (t < 192) { w2b_l[t] = W2b[t]; qw_l[t] = qw[t]; }
  for (int id = t; id < 384; id += 256) {
    sg_l[id] = 0.f;
    vq_l[id] = vq1[(size_t)(blockIdx.x * 2) * 192 + id];
  }
  for (int id = t; id < 1536; id += 256) {
    int r = id / 24, c = id % 24;
    const float* p = &sess[(size_t)(n0 + r) * 192 + c * 8];
    float4 f0 = *(const float4*)p;
    float4 f1 = *(const float4*)(p + 4);
    u32_t w0 = (u32_t)f2bf(f0.x) | ((u32_t)f2bf(f0.y) << 16);
    u32_t w1 = (u32_t)f2bf(f0.z) | ((u32_t)f2bf(f0.w) << 16);
    u32_t w2 = (u32_t)f2bf(f1.x) | ((u32_t)f2bf(f1.y) << 16);
    u32_t w3 = (u32_t)f2bf(f1.z) | ((u32_t)f2bf(f1.w) << 16);
    *(uint4*)(As + r * 512 + ((c ^ (r & 7)) << 4)) = make_uint4(w0, w1, w2, w3);
  }
  __syncthreads();
  int wv = t >> 6, lane = t & 63, li = lane & 15, lq = lane >> 4;
  int sl = wv >> 1;
  f32x4 acc[12];
#pragma unroll
  for (int sub = 0; sub < 12; sub++) acc[sub] = {0.f, 0.f, 0.f, 0.f};
#pragma unroll
  for (int ks = 0; ks < 6; ks++) {
    int r = wv * 16 + li;
    bf16x8 af = *(const bf16x8*)(As + r * 512 + (((ks * 4 + lq) ^ (r & 7)) << 4));
#pragma unroll
    for (int sub = 0; sub < 12; sub++) {
      bf16x8 bfr = *(const bf16x8*)&W2T[(size_t)(sub * 16 + li) * 192 + ks * 32 + lq * 8];
      acc[sub] = __builtin_amdgcn_mfma_f32_16x16x32_bf16(af, bfr, acc[sub], 0, 0, 0);
    }
  }
  float qbv = qb[0];
  float s_part[12];
#pragma unroll
  for (int sub = 0; sub < 12; sub++) s_part[sub] = 0.f;
#pragma unroll
  for (int rr = 0; rr < 4; rr++) {
    int n = n0 + wv * 16 + lq * 4 + rr;
    float ap = 0.f;
    float sv[12];
#pragma unroll
    for (int sub = 0; sub < 12; sub++) {
      int col = sub * 16 + li;
      float q = vq_l[sl * 192 + col] + acc[sub][rr] + w2b_l[col];
      float sgm = 1.f / (1.f + __expf(-q));
      ap += sgm * qw_l[col];
      sv[sub] = sess[(size_t)n * 192 + col];
    }
    ap = redu16(ap);
    float alpha = ap + qbv;
#pragma unroll
    for (int sub = 0; sub < 12; sub++) s_part[sub] += alpha * sv[sub];
  }
#pragma unroll
  for (int sub = 0; sub < 12; sub++) {
    float v = s_part[sub];
    v += __shfl_xor(v, 16, 64);
    v += __shfl_xor(v, 32, 64);
    if (lq == 0) atomicAdd(&sg_l[sl * 192 + sub * 16 + li], v);
  }
  __syncthreads();
  for (int id = t; id < 384; id += 256)
    sg[(size_t)(blockIdx.x * 2) * 192 + id] = sg_l[id];
}

__global__ __launch_bounds__(192) void k_sh(
    const float* __restrict__ vn, const float* __restrict__ sg,
    const float* __restrict__ W3w, const float* __restrict__ W3b,
    float* __restrict__ sh) {
  __shared__ float row[384];
  int b = blockIdx.x, j = threadIdx.x;
  row[j] = vn[b * 192 + j];
  row[192 + j] = sg[b * 192 + j];
  __syncthreads();
  float acc = W3b[j];
  for (int k = 0; k < 384; k++) acc += row[k] * W3w[k * 192 + j];
  sh[b * 192 + j] = acc;
}

// ---------------- final MFMA ----------------
__global__ __launch_bounds__(256) void k_final_mfma(
    const float* __restrict__ sh, const us_t* __restrict__ emb_bf,
    void* __restrict__ out, const int* __restrict__ flag) {
  __shared__ uint4 AsU[384];
  __shared__ uint4 BsU[2048];
  char* As = (char*)AsU;
  char* Bs = (char*)BsU;
  int t = threadIdx.x;
  int v0 = blockIdx.x * 256, b0 = blockIdx.y * 16;
  for (int id = t; id < 384; id += 256) {
    int i2 = id >> 7, rem = id & 127, r = rem >> 3, c = rem & 7;
    const float* p = &sh[(size_t)(b0 + r) * 192 + i2 * 64 + c * 8];
    float4 f0 = *(const float4*)p;
    float4 f1 = *(const float4*)(p + 4);
    u32_t w0 = (u32_t)f2bf(f0.x) | ((u32_t)f2bf(f0.y) << 16);
    u32_t w1 = (u32_t)f2bf(f0.z) | ((u32_t)f2bf(f0.w) << 16);
    u32_t w2 = (u32_t)f2bf(f1.x) | ((u32_t)f2bf(f1.y) << 16);
    u32_t w3 = (u32_t)f2bf(f1.z) | ((u32_t)f2bf(f1.w) << 16);
    *(uint4*)(As + i2 * 2048 + r * 128 + ((c ^ (r & 7)) << 4)) = make_uint4(w0, w1, w2, w3);
  }
  for (int id = t; id < 2048; id += 256) {
    int vr = id >> 3, c = id & 7;
    uint4 v = *(const uint4*)&emb_bf[(size_t)(v0 + vr) * 64 + c * 8];
    *(uint4*)(Bs + vr * 128 + ((c ^ (vr & 7)) << 4)) = v;
  }
  __syncthreads();
  int wv = t >> 6, lane = t & 63, li = lane & 15, lq = lane >> 4;
  int cb = wv * 64;
  int isbf = *flag;
  f32x4 acc[3][4];
#pragma unroll
  for (int i = 0; i < 3; i++)
#pragma unroll
    for (int sub = 0; sub < 4; sub++) acc[i][sub] = {0.f, 0.f, 0.f, 0.f};
#pragma unroll
  for (int ks = 0; ks < 2; ks++) {
    bf16x8 bfr[4];
#pragma unroll
    for (int sub = 0; sub < 4; sub++) {
      int vr = cb + sub * 16 + li;
      bfr[sub] = *(const bf16x8*)(Bs + vr * 128 + ((((ks << 2) | lq) ^ (vr & 7)) << 4));
    }
#pragma unroll
    for (int i = 0; i < 3; i++) {
      bf16x8 af = *(const bf16x8*)(As + i * 2048 + li * 128 + ((((ks << 2) | lq) ^ (li & 7)) << 4));
#pragma unroll
      for (int sub = 0; sub < 4; sub++)
        acc[i][sub] = __builtin_amdgcn_mfma_f32_16x16x32_bf16(af, bfr[sub], acc[i][sub], 0, 0, 0);
    }
  }
#pragma unroll
  for (int sub = 0; sub < 4; sub++) {
    int col = v0 + cb + sub * 16 + li;
#pragma unroll
    for (int rr = 0; rr < 4; rr++) {
      float o = fmaxf(fmaxf(acc[0][sub][rr], acc[1][sub][rr]), acc[2][sub][rr]);
      int b = b0 + lq * 4 + rr;
      if (isbf) ((us_t*)out)[(size_t)b * VV + col] = f2bf(o);
      else ((float*)out)[(size_t)b * VV + col] = o;
    }
  }
}

// ---------------- launcher ----------------
extern "C" void kernel_launch(void* const* d_in, const int* in_sizes, int n_in,
                              void* d_out, int out_size, void* d_ws, size_t ws_size,
                              hipStream_t stream) {
  if (n_in < 21) return;
  const int* x = (const int*)d_in[0];
  const int* ei = (const int*)d_in[1];

  char* ws = (char*)d_ws;
  size_t off = 0;
  auto A = [&](size_t bytes) -> char* {
    char* p = ws + off;
    off += (bytes + 255) & ~(size_t)255;
    return p;
  };
  int* flag = (int*)A(4);
  us_t* emb_bf = (us_t*)A((size_t)VV * 64 * 2);
  us_t* e_bf = (us_t*)A((size_t)NN * 64 * 2);
  us_t* g1Wt = (us_t*)A((size_t)3 * 65536 * 2);
  us_t* g2Wt = (us_t*)A((size_t)3 * 65536 * 2);
  us_t* W2T = (us_t*)A((size_t)36864 * 2);
  us_t* Waspack = (us_t*)A((size_t)96 * 64 * 2);
  float* eatt = (float*)A((size_t)NN * 96 * 4);
  float* c_g1as = (float*)A(3072 * 4);
  float* c_g1ad = (float*)A(3072 * 4);
  float* c_g1b = (float*)A(3072 * 4);
  float* c_g2as = (float*)A(192 * 4);
  float* c_g2ad = (float*)A(192 * 4);
  float* c_g2b = (float*)A(192 * 4);
  float* c_W1w = (float*)A(36864 * 4);
  float* c_W1b = (float*)A(192 * 4);
  float* c_W2b = (float*)A(192 * 4);
  float* c_qw = (float*)A(192 * 4);
  float* c_qb = (float*)A(4);
  float* c_W3w = (float*)A(73728 * 4);
  float* c_W3b = (float*)A(192 * 4);
  float* g_buf = (float*)A((size_t)NN * 4 * 4);
  us_t* xagg = (us_t*)A((size_t)3 * NN * 1024 * 2);
  us_t* Tbuf = (us_t*)A((size_t)3 * NN * 1024 * 2);
  float* h2pre = (float*)A((size_t)3 * NN * 64 * 4);
  float* a2s = (float*)A((size_t)3 * NN * 4);
  float* a2d = (float*)A((size_t)3 * NN * 4);
  float* sess = (float*)A((size_t)NN * 192 * 4);
  float* vq1 = (float*)A((size_t)BB * 192 * 4);
  float* sg = (float*)A((size_t)BB * 192 * 4);
  float* vn = (float*)A((size_t)BB * 192 * 4);
  float* shb = (float*)A((size_t)BB * 192 * 4);
  int* countsv = (int*)A((size_t)3 * NN * 4);
  int* offsetsv = (int*)A((size_t)(3 * NN + 1) * 4);
  int* fillposv = (int*)A((size_t)3 * NN * 4);
  int2* edgesC = (int2*)A((size_t)3 * EE * 8);
  float* easrcP = (float*)A((size_t)3 * EE * 16 * 4);
  if (off > ws_size) return;

  hipMemsetAsync(countsv, 0, 3 * NN * 4, stream);
  hipMemsetAsync(fillposv, 0, 3 * NN * 4, stream);

  k_detect<<<1, 64, 0, stream>>>(d_in[3], flag);

  PrepArgs pa;
  int nb = 0, idx = 0;
  auto SEC = [&](const void* s, void* d, int n, int kind) {
    pa.src[idx] = s; pa.dst[idx] = d; pa.n[idx] = n; pa.kind[idx] = kind;
    pa.start[idx] = nb; nb += (n + 255) / 256; idx++;
  };
  SEC(d_in[3], emb_bf, VV * 64, 1);
  SEC(d_in[5], g1Wt, 196608, 2);
  SEC(d_in[9], g2Wt, 196608, 3);
  SEC(d_in[15], W2T, 36864, 4);
  SEC(d_in[6], c_g1as, 3072, 0);
  SEC(d_in[7], c_g1ad, 3072, 0);
  SEC(d_in[8], c_g1b, 3072, 0);
  SEC(d_in[10], c_g2as, 192, 0);
  SEC(d_in[11], c_g2ad, 192, 0);
  SEC(d_in[12], c_g2b, 192, 0);
  SEC(d_in[13], c_W1w, 36864, 0);
  SEC(d_in[14], c_W1b, 192, 0);
  SEC(d_in[16], c_W2b, 192, 0);
  SEC(d_in[17], c_qw, 192, 0);
  SEC(d_in[18], c_qb, 1, 0);
  SEC(d_in[19], c_W3w, 73728, 0);
  SEC(d_in[20], c_W3b, 192, 0);
  pa.start[17] = nb;
  k_prep<<<nb, 256, 0, stream>>>(pa, flag);
  k_prepWa<<<24, 256, 0, stream>>>(d_in[5], c_g1as, c_g1ad, flag, Waspack);

  k_embed<<<NN * 64 / 256, 256, 0, stream>>>(x, d_in[3], d_in[4], flag, e_bf, g_buf);
  k_easrc<<<NN / 64, 256, 0, stream>>>(e_bf, Waspack, eatt);
  k_countv<<<EE / 256, 256, 0, stream>>>(ei, g_buf, countsv);
  k_scanv<<<1, 256, 0, stream>>>(countsv, offsetsv);
  k_fillv<<<EE / 256, 256, 0, stream>>>(ei, g_buf, eatt, offsetsv, fillposv,
                                        edgesC, easrcP);

  k_phaseA<<<dim3(NN / 4, 3), 256, 0, stream>>>(
      e_bf, g_buf, eatt, offsetsv, edgesC, easrcP, xagg);
  k_tgemm<<<dim3(NN / 64, 16, 3), 256, 0, stream>>>(xagg, g1Wt, c_g1b, Tbuf);
  k_h2gemm<<<dim3(NN / 64, 3), 256, 0, stream>>>(
      Tbuf, g2Wt, c_g2as, c_g2ad, h2pre, a2s, a2d);
  k_gat2_agg<<<dim3(NN * 64 / 256, 3), 256, 0, stream>>>(
      h2pre, a2s, a2d, c_g2b, offsetsv, edgesC, sess);

  k_vq1<<<BB, 192, 0, stream>>>(sess, c_W1w, c_W1b, vn, vq1);
  k_alpha_sg_mfma<<<NN / 64, 256, 0, stream>>>(sess, vq1, W2T, c_W2b, c_qw, c_qb, sg);
  k_sh<<<BB, 192, 0, stream>>>(vn, sg, c_W3w, c_W3b, shb);
  k_final_mfma<<<dim3(VV / 256, BB / 16), 256, 0, stream>>>(shb, emb_bf, d_out, flag);
}

// Round 14
// 267.855 us; speedup vs baseline: 1.0999x; 1.0999x over previous
//
#include <hip/hip_runtime.h>
#include <math.h>

#define NN 16384
#define EE 65536
#define BB 512
#define VV 32000

typedef unsigned short us_t;
typedef unsigned int u32_t;
typedef __attribute__((ext_vector_type(4))) float f32x4;
typedef __attribute__((ext_vector_type(8))) short bf16x8;
typedef __attribute__((ext_vector_type(4))) unsigned int u32x4;

__device__ __forceinline__ float bf2f(unsigned int u) {
  return __uint_as_float((u & 0xffffu) << 16);
}
__device__ __forceinline__ unsigned short f2bf(float f) {
  unsigned int x = __float_as_uint(f);
  unsigned int r = (x + 0x7fffu + ((x >> 16) & 1u)) >> 16;
  return (unsigned short)r;
}
__device__ __forceinline__ bf16x8 ntld(const us_t* p) {
  return __builtin_nontemporal_load((const bf16x8*)p);
}
__device__ __forceinline__ void ntst(us_t* p, u32_t a, u32_t b, u32_t c, u32_t d) {
  u32x4 v = {a, b, c, d};
  __builtin_nontemporal_store(v, (u32x4*)p);
}
__device__ __forceinline__ float wsum(float v) {
#pragma unroll
  for (int o = 32; o; o >>= 1) v += __shfl_xor(v, o, 64);
  return v;
}
__device__ __forceinline__ float redu16(float v) {
  v += __shfl_xor(v, 1, 64);
  v += __shfl_xor(v, 2, 64);
  v += __shfl_xor(v, 4, 64);
  v += __shfl_xor(v, 8, 64);
  return v;
}
__device__ __forceinline__ float lrelu(float x) { return x > 0.f ? x : 0.2f * x; }

// ---------------- dtype probe ----------------
__global__ void k_detect(const void* emb, int* flag) {
  if (threadIdx.x == 0 && blockIdx.x == 0) {
    const us_t* u = (const us_t*)emb;
    int ok = 1;
    for (int i = 0; i < 128; i++) {
      float v = bf2f((unsigned int)u[i]);
      if (!(fabsf(v) <= 0.13f)) { ok = 0; break; }
    }
    *flag = ok;  // 1 => inputs bf16, 0 => f32
  }
}

// ---------------- fused prep: convert + transpose weights ----------------
struct PrepArgs {
  const void* src[17];
  void* dst[17];
  int n[17];
  int kind[17];   // 0 cvt f32, 1 cvt bf16, 2 g1W T, 3 g2W T, 4 W2 T (192x192)
  int start[18];
};

__global__ void k_prep(PrepArgs pa, const int* __restrict__ flag) {
  int blk = blockIdx.x;
  int s = 0;
  while (s < 16 && blk >= pa.start[s + 1]) s++;
  int i = (blk - pa.start[s]) * 256 + threadIdx.x;
  if (i >= pa.n[s]) return;
  float v = (*flag) ? bf2f((unsigned int)((const us_t*)pa.src[s])[i])
                    : ((const float*)pa.src[s])[i];
  int kind = pa.kind[s];
  if (kind == 0) {
    ((float*)pa.dst[s])[i] = v;
  } else if (kind == 1) {
    ((us_t*)pa.dst[s])[i] = f2bf(v);
  } else if (kind == 2) {  // [3][64][1024] -> [3][1024][64]
    int ii = i >> 16, r = i & 65535, k = r >> 10, col = r & 1023;
    ((us_t*)pa.dst[s])[(ii << 16) + col * 64 + k] = f2bf(v);
  } else if (kind == 3) {  // [3][1024][64] -> [3][64][1024]
    int ii = i >> 16, r = i & 65535, k = r >> 6, col = r & 63;
    ((us_t*)pa.dst[s])[(ii << 16) + col * 1024 + k] = f2bf(v);
  } else {  // [192][192] -> [192][192]^T
    int k = i / 192, col = i % 192;
    ((us_t*)pa.dst[s])[col * 192 + k] = f2bf(v);
  }
}

// ---------------- Waspack: [96 cols][64 k] bf16; col = i*32 + sd*16 + h ----------------
__global__ void k_prepWa(const void* __restrict__ g1Wraw,
                         const float* __restrict__ g1as, const float* __restrict__ g1ad,
                         const int* __restrict__ flag, us_t* __restrict__ Waspack) {
  int gid = blockIdx.x * 256 + threadIdx.x;
  if (gid >= 96 * 64) return;
  int c = gid >> 6, k = gid & 63;
  int i = c >> 5, sd = (c >> 4) & 1, h = c & 15;
  const float* av = (sd ? g1ad : g1as) + i * 1024 + h * 64;
  size_t base = (size_t)i * 65536 + (size_t)k * 1024 + h * 64;
  int isbf = *flag;
  float s = 0.f;
  for (int d = 0; d < 64; d++) {
    float wv = isbf ? bf2f((unsigned int)((const us_t*)g1Wraw)[base + d])
                    : ((const float*)g1Wraw)[base + d];
    s += wv * av[d];
  }
  Waspack[c * 64 + k] = f2bf(s);
}

// ---------------- embedding gather + interest softmax ----------------
__global__ void k_embed(const int* __restrict__ x, const void* __restrict__ embr,
                        const void* __restrict__ wintr, const int* __restrict__ flag,
                        us_t* __restrict__ e_bf, float* __restrict__ g) {
  int gid = blockIdx.x * blockDim.x + threadIdx.x;
  int n = gid >> 6, lane = gid & 63;
  if (n >= NN) return;
  int isbf = *flag;
  size_t ei = (size_t)x[n] * 64 + lane;
  float v = isbf ? bf2f((unsigned int)((const us_t*)embr)[ei]) : ((const float*)embr)[ei];
  e_bf[(size_t)n * 64 + lane] = f2bf(v);
  float w0, w1, w2;
  if (isbf) {
    const us_t* w = (const us_t*)wintr;
    w0 = bf2f(w[lane * 3 + 0]); w1 = bf2f(w[lane * 3 + 1]); w2 = bf2f(w[lane * 3 + 2]);
  } else {
    const float* w = (const float*)wintr;
    w0 = w[lane * 3 + 0]; w1 = w[lane * 3 + 1]; w2 = w[lane * 3 + 2];
  }
  float t0 = wsum(v * w0), t1 = wsum(v * w1), t2 = wsum(v * w2);
  if (lane == 0) {
    float l0 = t0 / 0.1f, l1 = t1 / 0.1f, l2 = t2 / 0.1f;
    float m = fmaxf(l0, fmaxf(l1, l2));
    float p0 = __expf(l0 - m), p1 = __expf(l1 - m), p2 = __expf(l2 - m);
    float inv = 1.0f / (p0 + p1 + p2);
    g[n * 4 + 0] = p0 * inv; g[n * 4 + 1] = p1 * inv;
    g[n * 4 + 2] = p2 * inv; g[n * 4 + 3] = 0.f;
  }
}

// ---------------- compact per-interest CSR build (valid edges only) ----------------
__global__ void k_countv(const int* __restrict__ ei, const float* __restrict__ g,
                         int* __restrict__ countsv) {
  int e = blockIdx.x * 256 + threadIdx.x;
  if (e >= EE) return;
  int s = ei[e], d = ei[EE + e];
  const float thr = 1.0f / 3.0f;
#pragma unroll
  for (int i = 0; i < 3; i++) {
    if (g[s * 4 + i] > thr && g[d * 4 + i] > thr)
      atomicAdd(&countsv[i * NN + d], 1);
  }
}

__global__ void k_scanv(const int* __restrict__ counts, int* __restrict__ offsets) {
  __shared__ int part[256];
  __shared__ int excl[257];
  int t = threadIdx.x;
  int base = t * 192;
  int s = 0;
  for (int j = 0; j < 192; j++) s += counts[base + j];
  part[t] = s;
  __syncthreads();
  if (t == 0) {
    int run = 0;
    for (int j = 0; j < 256; j++) { excl[j] = run; run += part[j]; }
    excl[256] = run;
  }
  __syncthreads();
  int run = excl[t];
  for (int j = 0; j < 192; j++) { offsets[base + j] = run; run += counts[base + j]; }
  if (t == 255) offsets[3 * NN] = excl[256];
}

__global__ void k_fillv(const int* __restrict__ ei, const float* __restrict__ g,
                        const float* __restrict__ eatt,
                        const int* __restrict__ offsetsv, int* __restrict__ fillposv,
                        int2* __restrict__ edgesC, float* __restrict__ easrcP) {
  int e = blockIdx.x * 256 + threadIdx.x;
  if (e >= EE) return;
  int s = ei[e], d = ei[EE + e];
  const float thr = 1.0f / 3.0f;
#pragma unroll
  for (int i = 0; i < 3; i++) {
    float gs = g[s * 4 + i];
    if (gs > thr && g[d * 4 + i] > thr) {
      int pos = offsetsv[i * NN + d] + atomicAdd(&fillposv[i * NN + d], 1);
      edgesC[pos] = make_int2(s, __float_as_int(gs));
      const float* er = &eatt[(size_t)s * 96 + i * 32];
      float* op = &easrcP[(size_t)pos * 16];
#pragma unroll
      for (int h = 0; h < 16; h++) op[h] = gs * er[h];
    }
  }
}

// ---------------- easrc: e[N,64] @ Waspack^T -> eatt[N][96] f32 ----------------
__global__ __launch_bounds__(256) void k_easrc(
    const us_t* __restrict__ e_bf, const us_t* __restrict__ Waspack,
    float* __restrict__ eatt) {
  __shared__ char As[8192];
  int t = threadIdx.x;
  int row0 = blockIdx.x * 64;
  for (int id = t; id < 512; id += 256) {
    int r = id >> 3, c = id & 7;
    uint4 v = *(const uint4*)&e_bf[(size_t)(row0 + r) * 64 + c * 8];
    *(uint4*)(As + r * 128 + ((c ^ (r & 7)) << 4)) = v;
  }
  __syncthreads();
  int wv = t >> 6, L = t & 63, li = L & 15, lq = L >> 4;
#pragma unroll
  for (int ct = 0; ct < 6; ct++) {
    f32x4 acc = {0.f, 0.f, 0.f, 0.f};
#pragma unroll
    for (int ks = 0; ks < 2; ks++) {
      int row = wv * 16 + li;
      bf16x8 af = *(const bf16x8*)(As + row * 128 + (((ks * 4 + lq) ^ (row & 7)) << 4));
      bf16x8 bfr = *(const bf16x8*)(Waspack + (size_t)(ct * 16 + li) * 64 + ks * 32 + lq * 8);
      acc = __builtin_amdgcn_mfma_f32_16x16x32_bf16(af, bfr, acc, 0, 0, 0);
    }
#pragma unroll
    for (int r = 0; r < 4; r++) {
      int row = row0 + wv * 16 + lq * 4 + r;
      eatt[(size_t)row * 96 + ct * 16 + li] = acc[r];
    }
  }
}

// ---------------- Phase A: x-space aggregation -> xagg[3][16][N][64] bf16 head-major ----
__global__ __launch_bounds__(256) void k_phaseA(
    const us_t* __restrict__ e_bf, const float* __restrict__ g,
    const float* __restrict__ eatt,
    const int* __restrict__ offsetsv, const int2* __restrict__ edgesC,
    const float* __restrict__ easrcP, us_t* __restrict__ xagg) {
  int t = threadIdx.x;
  int intr = blockIdx.y;
  int wv = t >> 6, L = t & 63;
  int n = blockIdx.x * 4 + wv;
  int h = L >> 2;
  int doff = (L & 3) * 16;
  float gn = g[n * 4 + intr];
  float ad = gn * eatt[(size_t)n * 96 + intr * 32 + 16 + h];
  float m = lrelu(gn * eatt[(size_t)n * 96 + intr * 32 + h] + ad);
  float den = 1.f;
  float acc[16];
  {
    const uint4* ep = (const uint4*)&e_bf[(size_t)n * 64 + doff];
    uint4 a = ep[0], b = ep[1];
    acc[0] = gn * bf2f(a.x);  acc[1] = gn * bf2f(a.x >> 16);
    acc[2] = gn * bf2f(a.y);  acc[3] = gn * bf2f(a.y >> 16);
    acc[4] = gn * bf2f(a.z);  acc[5] = gn * bf2f(a.z >> 16);
    acc[6] = gn * bf2f(a.w);  acc[7] = gn * bf2f(a.w >> 16);
    acc[8] = gn * bf2f(b.x);  acc[9] = gn * bf2f(b.x >> 16);
    acc[10] = gn * bf2f(b.y); acc[11] = gn * bf2f(b.y >> 16);
    acc[12] = gn * bf2f(b.z); acc[13] = gn * bf2f(b.z >> 16);
    acc[14] = gn * bf2f(b.w); acc[15] = gn * bf2f(b.w >> 16);
  }
  int beg = offsetsv[intr * NN + n], end = offsetsv[intr * NN + n + 1];
  for (int j = beg; j < end; j++) {
    int2 sg = edgesC[j];
    int s = sg.x;
    float gs = __int_as_float(sg.y);
    float l = lrelu(easrcP[(size_t)j * 16 + h] + ad);
    float p = __expf(l - m);
    den += p;
    float pg = p * gs;
    const uint4* ep = (const uint4*)&e_bf[(size_t)s * 64 + doff];
    uint4 a = ep[0], b = ep[1];
    acc[0] += pg * bf2f(a.x);  acc[1] += pg * bf2f(a.x >> 16);
    acc[2] += pg * bf2f(a.y);  acc[3] += pg * bf2f(a.y >> 16);
    acc[4] += pg * bf2f(a.z);  acc[5] += pg * bf2f(a.z >> 16);
    acc[6] += pg * bf2f(a.w);  acc[7] += pg * bf2f(a.w >> 16);
    acc[8] += pg * bf2f(b.x);  acc[9] += pg * bf2f(b.x >> 16);
    acc[10] += pg * bf2f(b.y); acc[11] += pg * bf2f(b.y >> 16);
    acc[12] += pg * bf2f(b.z); acc[13] += pg * bf2f(b.z >> 16);
    acc[14] += pg * bf2f(b.w); acc[15] += pg * bf2f(b.w >> 16);
  }
  float inv = 1.f / den;
  u32_t w[8];
#pragma unroll
  for (int kk = 0; kk < 8; kk++) {
    w[kk] = (u32_t)f2bf(acc[2 * kk] * inv) | ((u32_t)f2bf(acc[2 * kk + 1] * inv) << 16);
  }
  us_t* op = &xagg[(((size_t)intr * 16 + h) * NN + n) * 64 + doff];
  ntst(op, w[0], w[1], w[2], w[3]);
  ntst(op + 8, w[4], w[5], w[6], w[7]);
}

// ---------------- fused T+h2 GEMM: h2 = relu(xagg@W1+b1) @ W2, no T in HBM ----------
// Per kb step (2 heads): stage xagg planes -> GEMM1 (W1 from L2) -> relu to Ts
// (wave-private row stripe, no barrier) -> GEMM2 accumulate.
__global__ __launch_bounds__(256) void k_h2gemm(
    const us_t* __restrict__ xagg, const us_t* __restrict__ g1Wt,
    const us_t* __restrict__ g2Wt, const float* __restrict__ b1all,
    const float* __restrict__ g2as, const float* __restrict__ g2ad,
    float* __restrict__ h2pre_a, float* __restrict__ a2s, float* __restrict__ a2d) {
  __shared__ char As[16384];
  __shared__ char Bs[16384];
  __shared__ char Ts[16384];
  __shared__ float b1s[1024];
  int t = threadIdx.x;
  int intr = blockIdx.y;
  int row0 = blockIdx.x * 64;
  const us_t* Wt1 = g1Wt + (size_t)intr * 65536;
  const us_t* Wt2 = g2Wt + (size_t)intr * 65536;
  const float* a_s = g2as + intr * 64;
  const float* a_d = g2ad + intr * 64;
  float* h2pre = h2pre_a + (size_t)intr * NN * 64;
  for (int id = t; id < 1024; id += 256) b1s[id] = b1all[intr * 1024 + id];
  int wv = t >> 6, lane = t & 63, li = lane & 15, lq = lane >> 4;
  f32x4 acc[4];
#pragma unroll
  for (int sub = 0; sub < 4; sub++) acc[sub] = {0.f, 0.f, 0.f, 0.f};
  for (int kb = 0; kb < 8; kb++) {
    int h0 = kb * 2;
    __syncthreads();
    for (int id = t; id < 1024; id += 256) {
      int r = id >> 4, c = id & 15;
      int hh = c >> 3, d = (c & 7) * 8;
      bf16x8 v = ntld(&xagg[(((size_t)intr * 16 + h0 + hh) * NN + row0 + r) * 64 + d]);
      *(bf16x8*)(As + r * 256 + ((c ^ (r & 15)) << 4)) = v;
      uint4 w = *(const uint4*)&Wt2[(size_t)r * 1024 + kb * 128 + c * 8];
      *(uint4*)(Bs + r * 256 + ((c ^ (r & 15)) << 4)) = w;
    }
    __syncthreads();
    // GEMM1: T rows wv*16..+15 x 128 tcols (2 heads); wave-private stripe
#pragma unroll
    for (int hh = 0; hh < 2; hh++) {
      int h = h0 + hh;
      f32x4 c1[4];
#pragma unroll
      for (int ct = 0; ct < 4; ct++) c1[ct] = {0.f, 0.f, 0.f, 0.f};
#pragma unroll
      for (int ks = 0; ks < 2; ks++) {
        int r = wv * 16 + li;
        int ca = hh * 8 + ks * 4 + lq;
        bf16x8 af = *(const bf16x8*)(As + r * 256 + ((ca ^ (r & 15)) << 4));
#pragma unroll
        for (int ct = 0; ct < 4; ct++) {
          bf16x8 bfr = *(const bf16x8*)&Wt1[(size_t)(h * 64 + ct * 16 + li) * 64 + ks * 32 + lq * 8];
          c1[ct] = __builtin_amdgcn_mfma_f32_16x16x32_bf16(af, bfr, c1[ct], 0, 0, 0);
        }
      }
#pragma unroll
      for (int ct = 0; ct < 4; ct++) {
        float bv = b1s[h * 64 + ct * 16 + li];
#pragma unroll
        for (int r = 0; r < 4; r++) {
          int row = wv * 16 + lq * 4 + r;
          int byte = (hh * 64 + ct * 16 + li) * 2;
          float tv = fmaxf(c1[ct][r] + bv, 0.f);
          *(us_t*)(Ts + row * 256 + (((byte >> 4) ^ (row & 15)) << 4) + (byte & 15)) = f2bf(tv);
        }
      }
    }
    // GEMM2: accumulate from own Ts stripe (same-wave ordering, no barrier)
#pragma unroll
    for (int ks = 0; ks < 4; ks++) {
      int r = wv * 16 + li;
      bf16x8 af = *(const bf16x8*)(Ts + r * 256 + ((((ks << 2) | lq) ^ (r & 15)) << 4));
#pragma unroll
      for (int sub = 0; sub < 4; sub++) {
        int vr = sub * 16 + li;
        bf16x8 bf_ = *(const bf16x8*)(Bs + vr * 256 + ((((ks << 2) | lq) ^ (vr & 15)) << 4));
        acc[sub] = __builtin_amdgcn_mfma_f32_16x16x32_bf16(af, bf_, acc[sub], 0, 0, 0);
      }
    }
  }
  float asv[4], adv[4];
#pragma unroll
  for (int sub = 0; sub < 4; sub++) {
    asv[sub] = a_s[sub * 16 + li];
    adv[sub] = a_d[sub * 16 + li];
  }
#pragma unroll
  for (int rr = 0; rr < 4; rr++) {
    int n = row0 + wv * 16 + lq * 4 + rr;
    float s = 0.f, d = 0.f;
#pragma unroll
    for (int sub = 0; sub < 4; sub++) {
      float hv = acc[sub][rr];
      h2pre[(size_t)n * 64 + sub * 16 + li] = hv;
      s += hv * asv[sub];
      d += hv * adv[sub];
    }
    s = redu16(s); d = redu16(d);
    if (li == 0) {
      a2s[(size_t)intr * NN + n] = s;
      a2d[(size_t)intr * NN + n] = d;
    }
  }
}

// ---------------- GAT2 aggregation (compact CSR, self-anchored) -> sess ----------------
__global__ void k_gat2_agg(const float* __restrict__ h2pre_a,
                           const float* __restrict__ a2s_a, const float* __restrict__ a2d_a,
                           const float* __restrict__ b2all,
                           const int* __restrict__ offsetsv,
                           const int2* __restrict__ edgesC, float* __restrict__ sess) {
  int intr = blockIdx.y;
  int gid = blockIdx.x * blockDim.x + threadIdx.x;
  int n = gid >> 6, lane = gid & 63;
  if (n >= NN) return;
  const float* h2pre = h2pre_a + (size_t)intr * NN * 64;
  const float* a2s = a2s_a + (size_t)intr * NN;
  const float* a2d = a2d_a + (size_t)intr * NN;
  const float* b2 = b2all + intr * 64;
  float ad = a2d[n];
  float m = lrelu(a2s[n] + ad);  // self anchor; softmax shift-invariant
  float den = 1.f;
  float acc = h2pre[(size_t)n * 64 + lane];
  int beg = offsetsv[intr * NN + n], end = offsetsv[intr * NN + n + 1];
  for (int j = beg; j < end; j++) {
    int s = edgesC[j].x;
    float l = lrelu(a2s[s] + ad);
    float p = __expf(l - m);
    den += p;
    acc += p * h2pre[(size_t)s * 64 + lane];
  }
  sess[(size_t)n * 192 + intr * 64 + lane] = acc / den + b2[lane];
}

// ---------------- scoring ----------------
__global__ __launch_bounds__(192) void k_vq1(
    const float* __restrict__ sess,
    const float* __restrict__ W1w, const float* __restrict__ W1b,
    float* __restrict__ vn, float* __restrict__ vq1) {
  __shared__ float row[192];
  int b = blockIdx.x, j = threadIdx.x;
  int li = b * 32 + 31;  // batch = repeat(arange(B),32)
  float v = sess[(size_t)li * 192 + j];
  row[j] = v;
  vn[b * 192 + j] = v;
  __syncthreads();
  float acc = W1b[j];
  for (int k = 0; k < 192; k++) acc += row[k] * W1w[k * 192 + j];
  vq1[b * 192 + j] = acc;
}

__global__ __launch_bounds__(256) void k_alpha_sg_mfma(
    const float* __restrict__ sess, const float* __restrict__ vq1,
    const us_t* __restrict__ W2T, const float* __restrict__ W2b,
    const float* __restrict__ qw, const float* __restrict__ qb,
    float* __restrict__ sg) {
  __shared__ char As[64 * 512];
  __shared__ float vq_l[2 * 192];
  __shared__ float w2b_l[192], qw_l[192];
  __shared__ float sg_l[2 * 192];
  int t = threadIdx.x;
  int n0 = blockIdx.x * 64;
  if (t < 192) { w2b_l[t] = W2b[t]; qw_l[t] = qw[t]; }
  for (int id = t; id < 384; id += 256) {
    sg_l[id] = 0.f;
    vq_l[id] = vq1[(size_t)(blockIdx.x * 2) * 192 + id];
  }
  for (int id = t; id < 1536; id += 256) {
    int r = id / 24, c = id % 24;
    const float* p = &sess[(size_t)(n0 + r) * 192 + c * 8];
    float4 f0 = *(const float4*)p;
    float4 f1 = *(const float4*)(p + 4);
    u32_t w0 = (u32_t)f2bf(f0.x) | ((u32_t)f2bf(f0.y) << 16);
    u32_t w1 = (u32_t)f2bf(f0.z) | ((u32_t)f2bf(f0.w) << 16);
    u32_t w2 = (u32_t)f2bf(f1.x) | ((u32_t)f2bf(f1.y) << 16);
    u32_t w3 = (u32_t)f2bf(f1.z) | ((u32_t)f2bf(f1.w) << 16);
    *(uint4*)(As + r * 512 + ((c ^ (r & 7)) << 4)) = make_uint4(w0, w1, w2, w3);
  }
  __syncthreads();
  int wv = t >> 6, lane = t & 63, li = lane & 15, lq = lane >> 4;
  int sl = wv >> 1;
  f32x4 acc[12];
#pragma unroll
  for (int sub = 0; sub < 12; sub++) acc[sub] = {0.f, 0.f, 0.f, 0.f};
#pragma unroll
  for (int ks = 0; ks < 6; ks++) {
    int r = wv * 16 + li;
    bf16x8 af = *(const bf16x8*)(As + r * 512 + (((ks * 4 + lq) ^ (r & 7)) << 4));
#pragma unroll
    for (int sub = 0; sub < 12; sub++) {
      bf16x8 bfr = *(const bf16x8*)&W2T[(size_t)(sub * 16 + li) * 192 + ks * 32 + lq * 8];
      acc[sub] = __builtin_amdgcn_mfma_f32_16x16x32_bf16(af, bfr, acc[sub], 0, 0, 0);
    }
  }
  float qbv = qb[0];
  float s_part[12];
#pragma unroll
  for (int sub = 0; sub < 12; sub++) s_part[sub] = 0.f;
#pragma unroll
  for (int rr = 0; rr < 4; rr++) {
    int n = n0 + wv * 16 + lq * 4 + rr;
    float ap = 0.f;
    float sv[12];
#pragma unroll
    for (int sub = 0; sub < 12; sub++) {
      int col = sub * 16 + li;
      float q = vq_l[sl * 192 + col] + acc[sub][rr] + w2b_l[col];
      float sgm = 1.f / (1.f + __expf(-q));
      ap += sgm * qw_l[col];
      sv[sub] = sess[(size_t)n * 192 + col];
    }
    ap = redu16(ap);
    float alpha = ap + qbv;
#pragma unroll
    for (int sub = 0; sub < 12; sub++) s_part[sub] += alpha * sv[sub];
  }
#pragma unroll
  for (int sub = 0; sub < 12; sub++) {
    float v = s_part[sub];
    v += __shfl_xor(v, 16, 64);
    v += __shfl_xor(v, 32, 64);
    if (lq == 0) atomicAdd(&sg_l[sl * 192 + sub * 16 + li], v);
  }
  __syncthreads();
  for (int id = t; id < 384; id += 256)
    sg[(size_t)(blockIdx.x * 2) * 192 + id] = sg_l[id];
}

__global__ __launch_bounds__(192) void k_sh(
    const float* __restrict__ vn, const float* __restrict__ sg,
    const float* __restrict__ W3w, const float* __restrict__ W3b,
    float* __restrict__ sh) {
  __shared__ float row[384];
  int b = blockIdx.x, j = threadIdx.x;
  row[j] = vn[b * 192 + j];
  row[192 + j] = sg[b * 192 + j];
  __syncthreads();
  float acc = W3b[j];
  for (int k = 0; k < 384; k++) acc += row[k] * W3w[k * 192 + j];
  sh[b * 192 + j] = acc;
}

// ---------------- final MFMA ----------------
__global__ __launch_bounds__(256) void k_final_mfma(
    const float* __restrict__ sh, const us_t* __restrict__ emb_bf,
    void* __restrict__ out, const int* __restrict__ flag) {
  __shared__ uint4 AsU[384];
  __shared__ uint4 BsU[2048];
  char* As = (char*)AsU;
  char* Bs = (char*)BsU;
  int t = threadIdx.x;
  int v0 = blockIdx.x * 256, b0 = blockIdx.y * 16;
  for (int id = t; id < 384; id += 256) {
    int i2 = id >> 7, rem = id & 127, r = rem >> 3, c = rem & 7;
    const float* p = &sh[(size_t)(b0 + r) * 192 + i2 * 64 + c * 8];
    float4 f0 = *(const float4*)p;
    float4 f1 = *(const float4*)(p + 4);
    u32_t w0 = (u32_t)f2bf(f0.x) | ((u32_t)f2bf(f0.y) << 16);
    u32_t w1 = (u32_t)f2bf(f0.z) | ((u32_t)f2bf(f0.w) << 16);
    u32_t w2 = (u32_t)f2bf(f1.x) | ((u32_t)f2bf(f1.y) << 16);
    u32_t w3 = (u32_t)f2bf(f1.z) | ((u32_t)f2bf(f1.w) << 16);
    *(uint4*)(As + i2 * 2048 + r * 128 + ((c ^ (r & 7)) << 4)) = make_uint4(w0, w1, w2, w3);
  }
  for (int id = t; id < 2048; id += 256) {
    int vr = id >> 3, c = id & 7;
    uint4 v = *(const uint4*)&emb_bf[(size_t)(v0 + vr) * 64 + c * 8];
    *(uint4*)(Bs + vr * 128 + ((c ^ (vr & 7)) << 4)) = v;
  }
  __syncthreads();
  int wv = t >> 6, lane = t & 63, li = lane & 15, lq = lane >> 4;
  int cb = wv * 64;
  int isbf = *flag;
  f32x4 acc[3][4];
#pragma unroll
  for (int i = 0; i < 3; i++)
#pragma unroll
    for (int sub = 0; sub < 4; sub++) acc[i][sub] = {0.f, 0.f, 0.f, 0.f};
#pragma unroll
  for (int ks = 0; ks < 2; ks++) {
    bf16x8 bfr[4];
#pragma unroll
    for (int sub = 0; sub < 4; sub++) {
      int vr = cb + sub * 16 + li;
      bfr[sub] = *(const bf16x8*)(Bs + vr * 128 + ((((ks << 2) | lq) ^ (vr & 7)) << 4));
    }
#pragma unroll
    for (int i = 0; i < 3; i++) {
      bf16x8 af = *(const bf16x8*)(As + i * 2048 + li * 128 + ((((ks << 2) | lq) ^ (li & 7)) << 4));
#pragma unroll
      for (int sub = 0; sub < 4; sub++)
        acc[i][sub] = __builtin_amdgcn_mfma_f32_16x16x32_bf16(af, bfr[sub], acc[i][sub], 0, 0, 0);
    }
  }
#pragma unroll
  for (int sub = 0; sub < 4; sub++) {
    int col = v0 + cb + sub * 16 + li;
#pragma unroll
    for (int rr = 0; rr < 4; rr++) {
      float o = fmaxf(fmaxf(acc[0][sub][rr], acc[1][sub][rr]), acc[2][sub][rr]);
      int b = b0 + lq * 4 + rr;
      if (isbf) ((us_t*)out)[(size_t)b * VV + col] = f2bf(o);
      else ((float*)out)[(size_t)b * VV + col] = o;
    }
  }
}

// ---------------- launcher ----------------
extern "C" void kernel_launch(void* const* d_in, const int* in_sizes, int n_in,
                              void* d_out, int out_size, void* d_ws, size_t ws_size,
                              hipStream_t stream) {
  if (n_in < 21) return;
  const int* x = (const int*)d_in[0];
  const int* ei = (const int*)d_in[1];

  char* ws = (char*)d_ws;
  size_t off = 0;
  auto A = [&](size_t bytes) -> char* {
    char* p = ws + off;
    off += (bytes + 255) & ~(size_t)255;
    return p;
  };
  int* flag = (int*)A(4);
  us_t* emb_bf = (us_t*)A((size_t)VV * 64 * 2);
  us_t* e_bf = (us_t*)A((size_t)NN * 64 * 2);
  us_t* g1Wt = (us_t*)A((size_t)3 * 65536 * 2);
  us_t* g2Wt = (us_t*)A((size_t)3 * 65536 * 2);
  us_t* W2T = (us_t*)A((size_t)36864 * 2);
  us_t* Waspack = (us_t*)A((size_t)96 * 64 * 2);
  float* eatt = (float*)A((size_t)NN * 96 * 4);
  float* c_g1as = (float*)A(3072 * 4);
  float* c_g1ad = (float*)A(3072 * 4);
  float* c_g1b = (float*)A(3072 * 4);
  float* c_g2as = (float*)A(192 * 4);
  float* c_g2ad = (float*)A(192 * 4);
  float* c_g2b = (float*)A(192 * 4);
  float* c_W1w = (float*)A(36864 * 4);
  float* c_W1b = (float*)A(192 * 4);
  float* c_W2b = (float*)A(192 * 4);
  float* c_qw = (float*)A(192 * 4);
  float* c_qb = (float*)A(4);
  float* c_W3w = (float*)A(73728 * 4);
  float* c_W3b = (float*)A(192 * 4);
  float* g_buf = (float*)A((size_t)NN * 4 * 4);
  us_t* xagg = (us_t*)A((size_t)3 * NN * 1024 * 2);
  float* h2pre = (float*)A((size_t)3 * NN * 64 * 4);
  float* a2s = (float*)A((size_t)3 * NN * 4);
  float* a2d = (float*)A((size_t)3 * NN * 4);
  float* sess = (float*)A((size_t)NN * 192 * 4);
  float* vq1 = (float*)A((size_t)BB * 192 * 4);
  float* sg = (float*)A((size_t)BB * 192 * 4);
  float* vn = (float*)A((size_t)BB * 192 * 4);
  float* shb = (float*)A((size_t)BB * 192 * 4);
  int* countsv = (int*)A((size_t)3 * NN * 4);
  int* offsetsv = (int*)A((size_t)(3 * NN + 1) * 4);
  int* fillposv = (int*)A((size_t)3 * NN * 4);
  int2* edgesC = (int2*)A((size_t)3 * EE * 8);
  float* easrcP = (float*)A((size_t)3 * EE * 16 * 4);
  if (off > ws_size) return;

  hipMemsetAsync(countsv, 0, 3 * NN * 4, stream);
  hipMemsetAsync(fillposv, 0, 3 * NN * 4, stream);

  k_detect<<<1, 64, 0, stream>>>(d_in[3], flag);

  PrepArgs pa;
  int nb = 0, idx = 0;
  auto SEC = [&](const void* s, void* d, int n, int kind) {
    pa.src[idx] = s; pa.dst[idx] = d; pa.n[idx] = n; pa.kind[idx] = kind;
    pa.start[idx] = nb; nb += (n + 255) / 256; idx++;
  };
  SEC(d_in[3], emb_bf, VV * 64, 1);
  SEC(d_in[5], g1Wt, 196608, 2);
  SEC(d_in[9], g2Wt, 196608, 3);
  SEC(d_in[15], W2T, 36864, 4);
  SEC(d_in[6], c_g1as, 3072, 0);
  SEC(d_in[7], c_g1ad, 3072, 0);
  SEC(d_in[8], c_g1b, 3072, 0);
  SEC(d_in[10], c_g2as, 192, 0);
  SEC(d_in[11], c_g2ad, 192, 0);
  SEC(d_in[12], c_g2b, 192, 0);
  SEC(d_in[13], c_W1w, 36864, 0);
  SEC(d_in[14], c_W1b, 192, 0);
  SEC(d_in[16], c_W2b, 192, 0);
  SEC(d_in[17], c_qw, 192, 0);
  SEC(d_in[18], c_qb, 1, 0);
  SEC(d_in[19], c_W3w, 73728, 0);
  SEC(d_in[20], c_W3b, 192, 0);
  pa.start[17] = nb;
  k_prep<<<nb, 256, 0, stream>>>(pa, flag);
  k_prepWa<<<24, 256, 0, stream>>>(d_in[5], c_g1as, c_g1ad, flag, Waspack);

  k_embed<<<NN * 64 / 256, 256, 0, stream>>>(x, d_in[3], d_in[4], flag, e_bf, g_buf);
  k_easrc<<<NN / 64, 256, 0, stream>>>(e_bf, Waspack, eatt);
  k_countv<<<EE / 256, 256, 0, stream>>>(ei, g_buf, countsv);
  k_scanv<<<1, 256, 0, stream>>>(countsv, offsetsv);
  k_fillv<<<EE / 256, 256, 0, stream>>>(ei, g_buf, eatt, offsetsv, fillposv,
                                        edgesC, easrcP);

  k_phaseA<<<dim3(NN / 4, 3), 256, 0, stream>>>(
      e_bf, g_buf, eatt, offsetsv, edgesC, easrcP, xagg);
  k_h2gemm<<<dim3(NN / 64, 3), 256, 0, stream>>>(
      xagg, g1Wt, g2Wt, c_g1b, c_g2as, c_g2ad, h2pre, a2s, a2d);
  k_gat2_agg<<<dim3(NN * 64 / 256, 3), 256, 0, stream>>>(
      h2pre, a2s, a2d, c_g2b, offsetsv, edgesC, sess);

  k_vq1<<<BB, 192, 0, stream>>>(sess, c_W1w, c_W1b, vn, vq1);
  k_alpha_sg_mfma<<<NN / 64, 256, 0, stream>>>(sess, vq1, W2T, c_W2b, c_qw, c_qb, sg);
  k_sh<<<BB, 192, 0, stream>>>(vn, sg, c_W3w, c_W3b, shb);
  k_final_mfma<<<dim3(VV / 256, BB / 16), 256, 0, stream>>>(shb, emb_bf, d_out, flag);
}